// Round 1
// baseline (1937.216 us; speedup 1.0000x reference)
//
#include <hip/hip_runtime.h>

// ---------------------------------------------------------------------------
// MambaLatentBiMap: 2 branches (fwd / reversed) x 2 mamba layers + gates.
// Both branches processed concurrently as row blocks: rows r = (j, b, l),
// j = branch (0..1), b = batch (0..3), l = seq (0..1023). 8192 rows total.
// Layer index for stage s, branch j: lidx = s + 2*j.
// ---------------------------------------------------------------------------

#define LSEQ 1024

__device__ __forceinline__ float sigmoidf_(float x) { return 1.f / (1.f + __expf(-x)); }
__device__ __forceinline__ float siluf_(float x)    { return x / (1.f + __expf(-x)); }
__device__ __forceinline__ float softplusf_(float x){ return x > 20.f ? x : log1pf(__expf(x)); }

// ---------------- prep: x (B,D,L) -> X0 rows (j,b,l) cols d, j=1 reversed ---
__global__ __launch_bounds__(256) void prep_kernel(const float* __restrict__ x,
                                                   float* __restrict__ X0) {
  long idx = (long)blockIdx.x * 256 + threadIdx.x;   // 2*4*1024*256 = 2,097,152
  int d = (int)(idx & 255);
  long t = idx >> 8;
  int l = (int)(t & 1023);
  int t2 = (int)(t >> 10);
  int b = t2 & 3;
  int j = t2 >> 2;
  int lsrc = j ? (1023 - l) : l;
  X0[idx] = x[((long)(b * 256 + d)) * LSEQ + lsrc];
}

// ---------------- Aneg = -exp(Alog), (4,256,32) ----------------------------
__global__ __launch_bounds__(256) void aneg_kernel(const float* __restrict__ Alog,
                                                   float* __restrict__ Aneg) {
  int idx = blockIdx.x * 256 + threadIdx.x;          // 32768
  Aneg[idx] = -__expf(Alog[idx]);
}

// ---------------- generic tiled fp32 GEMM ----------------------------------
// C[z] = A[z] (MxK, row major, lda) @ W[z] (KxN row-major, or NxK if TB) + epi
// EPI: 0 none, 1 bias+softplus, 2 bias+sigmoid
template <int EPI, bool TB>
__global__ __launch_bounds__(256)
void gemm_f32(const float* __restrict__ A, int lda, long aZ,
              const float* __restrict__ W, int ldw, long wZ,
              const float* __restrict__ Bias, long bZ,
              float* __restrict__ C, int ldc, long cZ,
              int M, int N, int K) {
  constexpr int BM = 128, BN = 64, BK = 16;
  __shared__ __align__(16) float As[BK][BM];
  __shared__ __align__(16) float Bs[BK][BN];
  const int z = blockIdx.z;
  A += (long)z * aZ;
  W += (long)z * wZ;
  C += (long)z * cZ;
  const float* bias = (EPI != 0) ? (Bias + (long)z * bZ) : nullptr;
  const int m0 = blockIdx.y * BM, n0 = blockIdx.x * BN;
  const int tid = threadIdx.x;
  const int tx = tid & 15, ty = tid >> 4;

  float acc[8][4];
#pragma unroll
  for (int i = 0; i < 8; ++i)
#pragma unroll
    for (int jn = 0; jn < 4; ++jn) acc[i][jn] = 0.f;

  for (int k0 = 0; k0 < K; k0 += BK) {
#pragma unroll
    for (int i = 0; i < 2; ++i) {               // A tile: 128x16 = 512 float4
      int idx = tid + i * 256;
      int m = idx >> 2, k4 = (idx & 3) << 2;
      float4 v = *(const float4*)(A + (long)(m0 + m) * lda + k0 + k4);
      As[k4 + 0][m] = v.x; As[k4 + 1][m] = v.y;
      As[k4 + 2][m] = v.z; As[k4 + 3][m] = v.w;
    }
    if (!TB) {                                   // W tile 16x64
      int k = tid >> 4, n4 = (tid & 15) << 2;
      float4 v = make_float4(0.f, 0.f, 0.f, 0.f);
      if (n0 + n4 < N) v = *(const float4*)(W + (long)(k0 + k) * ldw + n0 + n4);
      Bs[k][n4 + 0] = v.x; Bs[k][n4 + 1] = v.y;
      Bs[k][n4 + 2] = v.z; Bs[k][n4 + 3] = v.w;
    } else {                                     // W is (N,K): read rows of W
      int nn = tid >> 2, k4 = (tid & 3) << 2;
      float4 v = make_float4(0.f, 0.f, 0.f, 0.f);
      if (n0 + nn < N) v = *(const float4*)(W + (long)(n0 + nn) * ldw + k0 + k4);
      Bs[k4 + 0][nn] = v.x; Bs[k4 + 1][nn] = v.y;
      Bs[k4 + 2][nn] = v.z; Bs[k4 + 3][nn] = v.w;
    }
    __syncthreads();
#pragma unroll
    for (int kk = 0; kk < BK; ++kk) {
      float a[8], bb[4];
#pragma unroll
      for (int i = 0; i < 8; ++i) a[i] = As[kk][ty * 8 + i];
#pragma unroll
      for (int jn = 0; jn < 4; ++jn) bb[jn] = Bs[kk][tx * 4 + jn];
#pragma unroll
      for (int i = 0; i < 8; ++i)
#pragma unroll
        for (int jn = 0; jn < 4; ++jn) acc[i][jn] = fmaf(a[i], bb[jn], acc[i][jn]);
    }
    __syncthreads();
  }

  int n = n0 + tx * 4;
  if (n < N) {
#pragma unroll
    for (int i = 0; i < 8; ++i) {
      int m = m0 + ty * 8 + i;
      float4 v;
      float* vp = &v.x;
#pragma unroll
      for (int jn = 0; jn < 4; ++jn) {
        float val = acc[i][jn];
        if (EPI) val += bias[n + jn];
        if (EPI == 1) val = softplusf_(val);
        if (EPI == 2) val = sigmoidf_(val);
        vp[jn] = val;
      }
      *(float4*)(C + (long)m * ldc + n) = v;
    }
  }
}

// ---------------- causal conv4 + silu --------------------------------------
// UZ: rows (j,b,l) x 512 (u = cols 0..255, z = 256..511). uc = silu(conv(u)).
__global__ __launch_bounds__(256) void conv_kernel(const float* __restrict__ UZ,
                                                   const float* __restrict__ Wconv,
                                                   const float* __restrict__ bconv,
                                                   float* __restrict__ uc, int stage) {
  long idx = (long)blockIdx.x * 256 + threadIdx.x;  // 8192*256
  int di = (int)(idx & 255);
  long r = idx >> 8;
  int l = (int)(r & 1023);
  int j = (int)(r >> 12);
  int lidx = stage + 2 * j;
  const float* wc = Wconv + (long)(lidx * 256 + di) * 4;
  float acc = bconv[lidx * 256 + di];
  const float* up = UZ + (r - 3) * 512 + di;
  if (l >= 3) {
    acc = fmaf(up[0], wc[0], acc);
    acc = fmaf(up[512], wc[1], acc);
    acc = fmaf(up[1024], wc[2], acc);
    acc = fmaf(up[1536], wc[3], acc);
  } else {
    for (int k = 3 - l; k < 4; ++k) acc = fmaf(up[(long)k * 512], wc[k], acc);
  }
  uc[idx] = acc * sigmoidf_(acc);
}

// ---------------- selective scan -------------------------------------------
// thread = (channel c within block, state n). 8 channels/block, 32 states.
// grid: 8 (j,b) * 32 di-groups = 256 blocks.
__global__ __launch_bounds__(256) void scan_kernel(const float* __restrict__ dt,
                                                   const float* __restrict__ uc,
                                                   const float* __restrict__ UZ,
                                                   const float* __restrict__ proj,
                                                   const float* __restrict__ Aneg,
                                                   const float* __restrict__ Dskip,
                                                   float* __restrict__ yg, int stage) {
  int blk = blockIdx.x;
  int g = blk & 31;
  int jb = blk >> 5;                 // 0..7
  int c = threadIdx.x >> 5;          // 0..7
  int n = threadIdx.x & 31;
  int di = g * 8 + c;
  int j = jb >> 2;
  int lidx = stage + 2 * j;
  float Aval = Aneg[(long)(lidx * 256 + di) * 32 + n];
  float Dsk = Dskip[lidx * 256 + di];
  long r0 = (long)jb * 1024;
  const float* dtp = dt + r0 * 256 + di;
  const float* up  = uc + r0 * 256 + di;
  const float* zp  = UZ + r0 * 512 + 256 + di;
  const float* Bp  = proj + r0 * 80 + 16 + n;
  const float* Cp  = proj + r0 * 80 + 48 + n;
  float* yp = yg + r0 * 256 + di;
  float h = 0.f;
  for (int l = 0; l < 1024; ++l) {
    float dtv = dtp[(long)l * 256];
    float uv  = up[(long)l * 256];
    float Bn  = Bp[(long)l * 80];
    float Cn  = Cp[(long)l * 80];
    float a = __expf(dtv * Aval);
    h = fmaf(a, h, (dtv * uv) * Bn);
    float p = h * Cn;
    p += __shfl_xor(p, 16);
    p += __shfl_xor(p, 8);
    p += __shfl_xor(p, 4);
    p += __shfl_xor(p, 2);
    p += __shfl_xor(p, 1);
    if (n == 0) {
      float zv = zp[(long)l * 512];
      yp[(long)l * 256] = (p + uv * Dsk) * siluf_(zv);
    }
  }
}

// ---------------- final combine --------------------------------------------
// out[b,d,l] = (g0[l]*tanh(a0*H0[b,l,d]) + b0[l]) * gate0[b,d,l]
//            + (g1[l']*tanh(a1*H1[b,l',d]) + b1[l']) * gate1[b,d,l'], l'=1023-l
__global__ __launch_bounds__(256) void combine_kernel(const float* __restrict__ H,
                                                      const float* __restrict__ gate,
                                                      const float* __restrict__ alpha,
                                                      const float* __restrict__ gamma,
                                                      const float* __restrict__ beta,
                                                      float* __restrict__ out) {
  long idx = (long)blockIdx.x * 256 + threadIdx.x;  // 1,048,576 (b,d,l)
  int l = (int)(idx & 1023);
  long t = idx >> 10;
  int d = (int)(t & 255);
  int b = (int)(t >> 8);
  int lr = 1023 - l;
  float h0 = H[(((long)b * 1024 + l) * 256) + d];
  float h1 = H[(((long)(4 + b) * 1024 + lr) * 256) + d];
  float g0 = gate[((long)(b * 256 + d)) * 1024 + l];
  float g1 = gate[(long)1024 * 1024 + ((long)(b * 256 + d)) * 1024 + lr];
  float m0 = (gamma[l] * tanhf(alpha[0] * h0) + beta[l]) * g0;
  float m1 = (gamma[1024 + lr] * tanhf(alpha[1] * h1) + beta[1024 + lr]) * g1;
  out[idx] = m0 + m1;
}

// ---------------------------------------------------------------------------
extern "C" void kernel_launch(void* const* d_in, const int* in_sizes, int n_in,
                              void* d_out, int out_size, void* d_ws, size_t ws_size,
                              hipStream_t stream) {
  const float* x     = (const float*)d_in[0];
  const float* Win   = (const float*)d_in[1];
  const float* Wconv = (const float*)d_in[2];
  const float* bconv = (const float*)d_in[3];
  const float* Wxp   = (const float*)d_in[4];
  const float* Wdt   = (const float*)d_in[5];
  const float* bdt   = (const float*)d_in[6];
  const float* Alog  = (const float*)d_in[7];
  const float* Dskip = (const float*)d_in[8];
  const float* Wout  = (const float*)d_in[9];
  const float* Wg    = (const float*)d_in[10];
  const float* bg    = (const float*)d_in[11];
  const float* alpha = (const float*)d_in[12];
  const float* gamma = (const float*)d_in[13];
  const float* beta  = (const float*)d_in[14];
  float* out = (float*)d_out;

  float* ws   = (float*)d_ws;
  float* X0   = ws;                    // 8192*256
  float* X1   = X0 + 2097152;          // 8192*256
  float* UZ   = X1 + 2097152;          // 8192*512
  float* UC   = UZ + 4194304;          // 8192*256
  float* PROJ = UC + 2097152;          // 8192*80
  float* DT   = PROJ + 655360;         // 8192*256
  float* YG   = DT + 2097152;          // 8192*256
  float* GATE = YG + 2097152;          // 2*1024*1024
  float* ANEG = GATE + 2097152;        // 4*256*32

  prep_kernel<<<dim3(8192), dim3(256), 0, stream>>>(x, X0);
  aneg_kernel<<<dim3(128), dim3(256), 0, stream>>>(Alog, ANEG);

  // gates: C[j] = sigmoid(x(1024x1024) @ Wg[j]^T + bg[j])
  gemm_f32<2, true><<<dim3(16, 8, 2), dim3(256), 0, stream>>>(
      x, LSEQ, 0L, Wg, LSEQ, (long)LSEQ * LSEQ, bg, LSEQ,
      GATE, LSEQ, (long)LSEQ * LSEQ, 1024, 1024, 1024);

  for (int s = 0; s < 2; ++s) {
    const float* Xin = s ? X1 : X0;
    float* Xout = s ? X0 : X1;   // stage-1 output = H (X0 is dead by then)

    // GEMM1: UZ = Xin @ Win[lidx] (256 x 512)
    gemm_f32<0, false><<<dim3(8, 32, 2), dim3(256), 0, stream>>>(
        Xin, 256, (long)4096 * 256, Win + (long)s * 256 * 512, 512, (long)2 * 256 * 512,
        nullptr, 0, UZ, 512, (long)4096 * 512, 4096, 512, 256);

    conv_kernel<<<dim3(8192), dim3(256), 0, stream>>>(UZ, Wconv, bconv, UC, s);

    // GEMM2: PROJ = UC @ Wxp[lidx] (256 x 80)
    gemm_f32<0, false><<<dim3(2, 32, 2), dim3(256), 0, stream>>>(
        UC, 256, (long)4096 * 256, Wxp + (long)s * 256 * 80, 80, (long)2 * 256 * 80,
        nullptr, 0, PROJ, 80, (long)4096 * 80, 4096, 80, 256);

    // GEMM3: DT = softplus(PROJ[:, :16] @ Wdt[lidx] + bdt[lidx])
    gemm_f32<1, false><<<dim3(4, 32, 2), dim3(256), 0, stream>>>(
        PROJ, 80, (long)4096 * 80, Wdt + (long)s * 16 * 256, 256, (long)2 * 16 * 256,
        bdt + s * 256, 512, DT, 256, (long)4096 * 256, 4096, 256, 16);

    scan_kernel<<<dim3(256), dim3(256), 0, stream>>>(DT, UC, UZ, PROJ, ANEG, Dskip, YG, s);

    // GEMM4: Xout = YG @ Wout[lidx] (256 x 256)
    gemm_f32<0, false><<<dim3(4, 32, 2), dim3(256), 0, stream>>>(
        YG, 256, (long)4096 * 256, Wout + (long)s * 256 * 256, 256, (long)2 * 256 * 256,
        nullptr, 0, Xout, 256, (long)4096 * 256, 4096, 256, 256);
  }

  combine_kernel<<<dim3(4096), dim3(256), 0, stream>>>(X0, GATE, alpha, gamma, beta, out);
}

// Round 2
// 461.435 us; speedup vs baseline: 4.1982x; 4.1982x over previous
//
#include <hip/hip_runtime.h>

// ---------------------------------------------------------------------------
// MambaLatentBiMap: 2 branches (fwd / reversed) x 2 mamba layers + gates.
// Rows r = (j, b, l): j = branch (0..1), b = batch (0..3), l = seq (0..1023).
// 8192 rows total. Layer index for stage s, branch j: lidx = s + 2*j.
// Selective scan: chunked linear-recurrence (pass1 per-chunk zero-init scan,
// pass2 sequential chunk combine via exp(A*sum_dt), pass3 rerun with hstart).
// ---------------------------------------------------------------------------

#define LSEQ 1024
#define SCAN_CL 16   // chunk length
#define SCAN_NC 64   // chunks per sequence

__device__ __forceinline__ float sigmoidf_(float x) { return 1.f / (1.f + __expf(-x)); }
__device__ __forceinline__ float siluf_(float x)    { return x / (1.f + __expf(-x)); }
__device__ __forceinline__ float softplusf_(float x){ return x > 20.f ? x : log1pf(__expf(x)); }

// ---------------- prep: x (B,D,L) -> X0 rows (j,b,l) cols d, j=1 reversed ---
__global__ __launch_bounds__(256) void prep_kernel(const float* __restrict__ x,
                                                   float* __restrict__ X0) {
  long idx = (long)blockIdx.x * 256 + threadIdx.x;   // 2*4*1024*256 = 2,097,152
  int d = (int)(idx & 255);
  long t = idx >> 8;
  int l = (int)(t & 1023);
  int t2 = (int)(t >> 10);
  int b = t2 & 3;
  int j = t2 >> 2;
  int lsrc = j ? (1023 - l) : l;
  X0[idx] = x[((long)(b * 256 + d)) * LSEQ + lsrc];
}

// ---------------- Aneg = -exp(Alog), (4,256,32) ----------------------------
__global__ __launch_bounds__(256) void aneg_kernel(const float* __restrict__ Alog,
                                                   float* __restrict__ Aneg) {
  int idx = blockIdx.x * 256 + threadIdx.x;          // 32768
  Aneg[idx] = -__expf(Alog[idx]);
}

// ---------------- generic tiled fp32 GEMM ----------------------------------
// C[z] = A[z] (MxK, row major, lda) @ W[z] (KxN row-major, or NxK if TB) + epi
// EPI: 0 none, 1 bias+softplus, 2 bias+sigmoid
template <int EPI, bool TB>
__global__ __launch_bounds__(256)
void gemm_f32(const float* __restrict__ A, int lda, long aZ,
              const float* __restrict__ W, int ldw, long wZ,
              const float* __restrict__ Bias, long bZ,
              float* __restrict__ C, int ldc, long cZ,
              int M, int N, int K) {
  constexpr int BM = 128, BN = 64, BK = 16;
  __shared__ __align__(16) float As[BK][BM];
  __shared__ __align__(16) float Bs[BK][BN];
  const int z = blockIdx.z;
  A += (long)z * aZ;
  W += (long)z * wZ;
  C += (long)z * cZ;
  const float* bias = (EPI != 0) ? (Bias + (long)z * bZ) : nullptr;
  const int m0 = blockIdx.y * BM, n0 = blockIdx.x * BN;
  const int tid = threadIdx.x;
  const int tx = tid & 15, ty = tid >> 4;

  float acc[8][4];
#pragma unroll
  for (int i = 0; i < 8; ++i)
#pragma unroll
    for (int jn = 0; jn < 4; ++jn) acc[i][jn] = 0.f;

  for (int k0 = 0; k0 < K; k0 += BK) {
#pragma unroll
    for (int i = 0; i < 2; ++i) {               // A tile: 128x16 = 512 float4
      int idx = tid + i * 256;
      int m = idx >> 2, k4 = (idx & 3) << 2;
      float4 v = *(const float4*)(A + (long)(m0 + m) * lda + k0 + k4);
      As[k4 + 0][m] = v.x; As[k4 + 1][m] = v.y;
      As[k4 + 2][m] = v.z; As[k4 + 3][m] = v.w;
    }
    if (!TB) {                                   // W tile 16x64
      int k = tid >> 4, n4 = (tid & 15) << 2;
      float4 v = make_float4(0.f, 0.f, 0.f, 0.f);
      if (n0 + n4 < N) v = *(const float4*)(W + (long)(k0 + k) * ldw + n0 + n4);
      Bs[k][n4 + 0] = v.x; Bs[k][n4 + 1] = v.y;
      Bs[k][n4 + 2] = v.z; Bs[k][n4 + 3] = v.w;
    } else {                                     // W is (N,K): read rows of W
      int nn = tid >> 2, k4 = (tid & 3) << 2;
      float4 v = make_float4(0.f, 0.f, 0.f, 0.f);
      if (n0 + nn < N) v = *(const float4*)(W + (long)(n0 + nn) * ldw + k0 + k4);
      Bs[k4 + 0][nn] = v.x; Bs[k4 + 1][nn] = v.y;
      Bs[k4 + 2][nn] = v.z; Bs[k4 + 3][nn] = v.w;
    }
    __syncthreads();
#pragma unroll
    for (int kk = 0; kk < BK; ++kk) {
      float a[8], bb[4];
#pragma unroll
      for (int i = 0; i < 8; ++i) a[i] = As[kk][ty * 8 + i];
#pragma unroll
      for (int jn = 0; jn < 4; ++jn) bb[jn] = Bs[kk][tx * 4 + jn];
#pragma unroll
      for (int i = 0; i < 8; ++i)
#pragma unroll
        for (int jn = 0; jn < 4; ++jn) acc[i][jn] = fmaf(a[i], bb[jn], acc[i][jn]);
    }
    __syncthreads();
  }

  int n = n0 + tx * 4;
  if (n < N) {
#pragma unroll
    for (int i = 0; i < 8; ++i) {
      int m = m0 + ty * 8 + i;
      float4 v;
      float* vp = &v.x;
#pragma unroll
      for (int jn = 0; jn < 4; ++jn) {
        float val = acc[i][jn];
        if (EPI) val += bias[n + jn];
        if (EPI == 1) val = softplusf_(val);
        if (EPI == 2) val = sigmoidf_(val);
        vp[jn] = val;
      }
      *(float4*)(C + (long)m * ldc + n) = v;
    }
  }
}

// ---------------- causal conv4 + silu --------------------------------------
// UZ: rows (j,b,l) x 512 (u = cols 0..255, z = 256..511). uc = silu(conv(u)).
__global__ __launch_bounds__(256) void conv_kernel(const float* __restrict__ UZ,
                                                   const float* __restrict__ Wconv,
                                                   const float* __restrict__ bconv,
                                                   float* __restrict__ uc, int stage) {
  long idx = (long)blockIdx.x * 256 + threadIdx.x;  // 8192*256
  int di = (int)(idx & 255);
  long r = idx >> 8;
  int l = (int)(r & 1023);
  int j = (int)(r >> 12);
  int lidx = stage + 2 * j;
  const float* wc = Wconv + (long)(lidx * 256 + di) * 4;
  float acc = bconv[lidx * 256 + di];
  const float* up = UZ + (r - 3) * 512 + di;
  if (l >= 3) {
    acc = fmaf(up[0], wc[0], acc);
    acc = fmaf(up[512], wc[1], acc);
    acc = fmaf(up[1024], wc[2], acc);
    acc = fmaf(up[1536], wc[3], acc);
  } else {
    for (int k = 3 - l; k < 4; ++k) acc = fmaf(up[(long)k * 512], wc[k], acc);
  }
  uc[idx] = acc * sigmoidf_(acc);
}

// ---------------- selective scan: chunked ----------------------------------
// Pass 0: per-chunk scan with h=0; writes end state (32/ch) + sum(dt) per ch.
// Pass 1: per-chunk scan from hstart (read from HST); writes y with epilogue.
// thread = channel di (0..255), 32 states in registers.
// grid = 8 (j,b) * SCAN_NC chunks.
template <int PASS>
__global__ __launch_bounds__(256)
void scan_chunk_kernel(const float* __restrict__ dt,
                       const float* __restrict__ uc,
                       const float* __restrict__ UZ,
                       const float* __restrict__ proj,
                       const float* __restrict__ Aneg,
                       const float* __restrict__ Dskip,
                       float* __restrict__ HST,   // [8][NC][256][32]
                       float* __restrict__ DTS,   // [8][NC][256]
                       float* __restrict__ yg, int stage) {
  __shared__ __align__(16) float BC[SCAN_CL][64];  // per-l: B[0..31], C[32..63]
  const int blk = blockIdx.x;
  const int chunk = blk & (SCAN_NC - 1);
  const int jb = blk >> 6;                 // 0..7
  const int di = threadIdx.x;
  const int j = jb >> 2;
  const int lidx = stage + 2 * j;
  const long r0 = (long)jb * 1024 + (long)chunk * SCAN_CL;

  // stage B,C for the chunk into LDS (proj cols 16..79 are contiguous B|C)
  for (int e = threadIdx.x; e < SCAN_CL * 64; e += 256) {
    int l = e >> 6, col = e & 63;
    BC[l][col] = proj[(r0 + l) * 80 + 16 + col];
  }

  float A[32];
  {
    const float4* ap = (const float4*)(Aneg + ((long)(lidx * 256 + di)) * 32);
#pragma unroll
    for (int q = 0; q < 8; ++q) {
      float4 v = ap[q];
      A[4 * q] = v.x; A[4 * q + 1] = v.y; A[4 * q + 2] = v.z; A[4 * q + 3] = v.w;
    }
  }

  const long sbase = (((long)jb * SCAN_NC + chunk) * 256 + di) * 32;
  float h[32];
  if (PASS == 0) {
#pragma unroll
    for (int n = 0; n < 32; ++n) h[n] = 0.f;
  } else {
    const float4* hp = (const float4*)(HST + sbase);
#pragma unroll
    for (int q = 0; q < 8; ++q) {
      float4 v = hp[q];
      h[4 * q] = v.x; h[4 * q + 1] = v.y; h[4 * q + 2] = v.z; h[4 * q + 3] = v.w;
    }
  }

  float Dsk = 0.f, dtsum = 0.f;
  if (PASS == 1) Dsk = Dskip[lidx * 256 + di];

  __syncthreads();

  for (int l = 0; l < SCAN_CL; ++l) {
    const long r = r0 + l;
    float dtv = dt[r * 256 + di];
    float uv  = uc[r * 256 + di];
    float du  = dtv * uv;
    if (PASS == 0) dtsum += dtv;
    float yacc[4] = {0.f, 0.f, 0.f, 0.f};
    const float4* bc4 = (const float4*)&BC[l][0];
#pragma unroll
    for (int q = 0; q < 8; ++q) {
      float4 bv = bc4[q];
      float4 cv = bc4[8 + q];
      const float* bp = &bv.x;
      const float* cp = &cv.x;
#pragma unroll
      for (int k = 0; k < 4; ++k) {
        int n = 4 * q + k;
        float a = __expf(dtv * A[n]);
        h[n] = fmaf(a, h[n], du * bp[k]);
        yacc[n & 3] = fmaf(h[n], cp[k], yacc[n & 3]);
      }
    }
    if (PASS == 1) {
      float y = (yacc[0] + yacc[1]) + (yacc[2] + yacc[3]);
      float zv = UZ[r * 512 + 256 + di];
      yg[r * 256 + di] = (y + uv * Dsk) * siluf_(zv);
    }
  }

  if (PASS == 0) {
    float4* hp = (float4*)(HST + sbase);
#pragma unroll
    for (int q = 0; q < 8; ++q)
      hp[q] = make_float4(h[4 * q], h[4 * q + 1], h[4 * q + 2], h[4 * q + 3]);
    DTS[((long)jb * SCAN_NC + chunk) * 256 + di] = dtsum;
  }
}

// ---------------- scan pass 2: sequential chunk combine (in-place) ---------
// thread = (jb, di, n). hstart_{c+1} = exp(A*dts_c) * hstart_c + s_c.
// Reads s_c from HST[c], overwrites HST[c] with hstart_c (read-before-write).
__global__ __launch_bounds__(256)
void scan_combine_kernel(float* __restrict__ HST, const float* __restrict__ DTS,
                         const float* __restrict__ Aneg, int stage) {
  int t = blockIdx.x * 256 + threadIdx.x;   // 8*256*32 = 65536
  int n = t & 31;
  int di = (t >> 5) & 255;
  int jb = t >> 13;
  int lidx = stage + 2 * (jb >> 2);
  float A = Aneg[((long)(lidx * 256 + di)) * 32 + n];
  float hs = 0.f;
  for (int c = 0; c < SCAN_NC; ++c) {
    long base = ((long)jb * SCAN_NC + c) * 256 + di;
    long idx = base * 32 + n;
    float s = HST[idx];
    HST[idx] = hs;
    float P = __expf(A * DTS[base]);
    hs = fmaf(P, hs, s);
  }
}

// ---------------- final combine --------------------------------------------
__global__ __launch_bounds__(256) void combine_kernel(const float* __restrict__ H,
                                                      const float* __restrict__ gate,
                                                      const float* __restrict__ alpha,
                                                      const float* __restrict__ gamma,
                                                      const float* __restrict__ beta,
                                                      float* __restrict__ out) {
  long idx = (long)blockIdx.x * 256 + threadIdx.x;  // 1,048,576 (b,d,l)
  int l = (int)(idx & 1023);
  long t = idx >> 10;
  int d = (int)(t & 255);
  int b = (int)(t >> 8);
  int lr = 1023 - l;
  float h0 = H[(((long)b * 1024 + l) * 256) + d];
  float h1 = H[(((long)(4 + b) * 1024 + lr) * 256) + d];
  float g0 = gate[((long)(b * 256 + d)) * 1024 + l];
  float g1 = gate[(long)1024 * 1024 + ((long)(b * 256 + d)) * 1024 + lr];
  float m0 = (gamma[l] * tanhf(alpha[0] * h0) + beta[l]) * g0;
  float m1 = (gamma[1024 + lr] * tanhf(alpha[1] * h1) + beta[1024 + lr]) * g1;
  out[idx] = m0 + m1;
}

// ---------------------------------------------------------------------------
extern "C" void kernel_launch(void* const* d_in, const int* in_sizes, int n_in,
                              void* d_out, int out_size, void* d_ws, size_t ws_size,
                              hipStream_t stream) {
  const float* x     = (const float*)d_in[0];
  const float* Win   = (const float*)d_in[1];
  const float* Wconv = (const float*)d_in[2];
  const float* bconv = (const float*)d_in[3];
  const float* Wxp   = (const float*)d_in[4];
  const float* Wdt   = (const float*)d_in[5];
  const float* bdt   = (const float*)d_in[6];
  const float* Alog  = (const float*)d_in[7];
  const float* Dskip = (const float*)d_in[8];
  const float* Wout  = (const float*)d_in[9];
  const float* Wg    = (const float*)d_in[10];
  const float* bg    = (const float*)d_in[11];
  const float* alpha = (const float*)d_in[12];
  const float* gamma = (const float*)d_in[13];
  const float* beta  = (const float*)d_in[14];
  float* out = (float*)d_out;

  float* ws   = (float*)d_ws;
  float* X0   = ws;                    // 8192*256  = 2,097,152
  float* X1   = X0 + 2097152;          // 2,097,152
  float* UZ   = X1 + 2097152;          // 8192*512  = 4,194,304
  float* UC   = UZ + 4194304;          // 2,097,152
  float* PROJ = UC + 2097152;          // 8192*80   = 655,360
  float* DT   = PROJ + 655360;         // 2,097,152
  float* YG   = DT + 2097152;          // 2,097,152
  float* GATE = YG + 2097152;          // 2*1024*1024 = 2,097,152
  float* ANEG = GATE + 2097152;        // 32,768
  float* HST  = ANEG + 32768;          // 8*64*256*32 = 4,194,304
  float* DTS  = HST + 4194304;         // 8*64*256 = 131,072
  // total: 21,790,720 floats = 87.2 MB

  prep_kernel<<<dim3(8192), dim3(256), 0, stream>>>(x, X0);
  aneg_kernel<<<dim3(128), dim3(256), 0, stream>>>(Alog, ANEG);

  // gates: C[j] = sigmoid(x(1024x1024) @ Wg[j]^T + bg[j])
  gemm_f32<2, true><<<dim3(16, 8, 2), dim3(256), 0, stream>>>(
      x, LSEQ, 0L, Wg, LSEQ, (long)LSEQ * LSEQ, bg, LSEQ,
      GATE, LSEQ, (long)LSEQ * LSEQ, 1024, 1024, 1024);

  for (int s = 0; s < 2; ++s) {
    const float* Xin = s ? X1 : X0;
    float* Xout = s ? X0 : X1;   // stage-1 output = H (X0 is dead by then)

    // GEMM1: UZ = Xin @ Win[lidx] (256 x 512)
    gemm_f32<0, false><<<dim3(8, 32, 2), dim3(256), 0, stream>>>(
        Xin, 256, (long)4096 * 256, Win + (long)s * 256 * 512, 512, (long)2 * 256 * 512,
        nullptr, 0, UZ, 512, (long)4096 * 512, 4096, 512, 256);

    conv_kernel<<<dim3(8192), dim3(256), 0, stream>>>(UZ, Wconv, bconv, UC, s);

    // GEMM2: PROJ = UC @ Wxp[lidx] (256 x 80)
    gemm_f32<0, false><<<dim3(2, 32, 2), dim3(256), 0, stream>>>(
        UC, 256, (long)4096 * 256, Wxp + (long)s * 256 * 80, 80, (long)2 * 256 * 80,
        nullptr, 0, PROJ, 80, (long)4096 * 80, 4096, 80, 256);

    // GEMM3: DT = softplus(PROJ[:, :16] @ Wdt[lidx] + bdt[lidx])
    gemm_f32<1, false><<<dim3(4, 32, 2), dim3(256), 0, stream>>>(
        PROJ, 80, (long)4096 * 80, Wdt + (long)s * 16 * 256, 256, (long)2 * 16 * 256,
        bdt + s * 256, 512, DT, 256, (long)4096 * 256, 4096, 256, 16);

    // chunked selective scan
    scan_chunk_kernel<0><<<dim3(8 * SCAN_NC), dim3(256), 0, stream>>>(
        DT, UC, UZ, PROJ, ANEG, Dskip, HST, DTS, YG, s);
    scan_combine_kernel<<<dim3(256), dim3(256), 0, stream>>>(HST, DTS, ANEG, s);
    scan_chunk_kernel<1><<<dim3(8 * SCAN_NC), dim3(256), 0, stream>>>(
        DT, UC, UZ, PROJ, ANEG, Dskip, HST, DTS, YG, s);

    // GEMM4: Xout = YG @ Wout[lidx] (256 x 256)
    gemm_f32<0, false><<<dim3(4, 32, 2), dim3(256), 0, stream>>>(
        YG, 256, (long)4096 * 256, Wout + (long)s * 256 * 256, 256, (long)2 * 256 * 256,
        nullptr, 0, Xout, 256, (long)4096 * 256, 4096, 256, 256);
  }

  combine_kernel<<<dim3(4096), dim3(256), 0, stream>>>(X0, GATE, alpha, gamma, beta, out);
}